// Round 6
// baseline (1813.833 us; speedup 1.0000x reference)
//
#include <hip/hip_runtime.h>
#include <hip/hip_bf16.h>
#include <cstdint>

typedef __bf16 bf16_t;
typedef __bf16 bf16x8 __attribute__((ext_vector_type(8)));
typedef float f32x4 __attribute__((ext_vector_type(4)));

#define DEV_INLINE __device__ __forceinline__

#define NTOK 8192
#define DDIM 1024
#define HDIM 4096
#define SDIM 1024
#define NEXP 8
#define HEXP 512
#define TSEQ 2048

#define VMCNT(n) asm volatile("s_waitcnt vmcnt(" #n ")" ::: "memory")
#define BARF() asm volatile("s_barrier" ::: "memory")

// ---------------- conversion: f32 -> bf16, 8 elems/thread ----------------
__global__ __launch_bounds__(256) void k_f32_to_bf16(const float* __restrict__ src,
                                                     bf16_t* __restrict__ dst, int n8) {
  int i = blockIdx.x * 256 + threadIdx.x;
  if (i >= n8) return;
  const float4* s = (const float4*)src + (size_t)i * 2;
  float4 v0 = s[0], v1 = s[1];
  bf16x8 o;
  o[0] = (bf16_t)v0.x; o[1] = (bf16_t)v0.y; o[2] = (bf16_t)v0.z; o[3] = (bf16_t)v0.w;
  o[4] = (bf16_t)v1.x; o[5] = (bf16_t)v1.y; o[6] = (bf16_t)v1.z; o[7] = (bf16_t)v1.w;
  *((bf16x8*)dst + i) = o;
}

// ------------- conv weight: [S][S][K] f32 -> [S][K*S] bf16 (k-major) -------------
__global__ __launch_bounds__(256) void k_convw(const float* __restrict__ src,
                                               bf16_t* __restrict__ dst) {
  int i = blockIdx.x * 256 + threadIdx.x;
  size_t flat = (size_t)i * 8;
  int s = (int)(flat >> 12);
  int col = (int)(flat & 4095);
  int k = col >> 10;
  int si0 = col & 1023;
  const float* sp = src + (size_t)s * 4096 + k;
  bf16x8 o;
#pragma unroll
  for (int j = 0; j < 8; ++j) o[j] = (bf16_t)sp[(size_t)(si0 + j) * 4];
  *(bf16x8*)(dst + flat) = o;
}

// ------------- im2col: h[8192][1024] -> A2[8192][4096], A2[t][k*1024+si]=h[t-3+k][si] -------------
__global__ __launch_bounds__(256) void k_im2col(const bf16_t* __restrict__ h,
                                                bf16_t* __restrict__ a2) {
  int i = blockIdx.x * 256 + threadIdx.x;
  size_t flat = (size_t)i * 8;
  int t = (int)(flat >> 12);
  int col = (int)(flat & 4095);
  int k = col >> 10;
  int si = col & 1023;
  int tt = t & (TSEQ - 1);
  bf16x8 v;
#pragma unroll
  for (int j = 0; j < 8; ++j) v[j] = (bf16_t)0.f;
  if (tt - 3 + k >= 0) v = *(const bf16x8*)(h + (size_t)(t - 3 + k) * SDIM + si);
  *(bf16x8*)(a2 + flat) = v;
}

// ------------- router: branch softmax [8192,3] + MoE top-2 combine*bw2 [8192,8] -------------
__global__ __launch_bounds__(256) void k_router(const float* __restrict__ x,
                                                const float* __restrict__ rW,
                                                const float* __restrict__ rb,
                                                const float* __restrict__ mW,
                                                const float* __restrict__ mb,
                                                float* __restrict__ bw3,
                                                float* __restrict__ comb) {
  int wave = threadIdx.x >> 6, lane = threadIdx.x & 63;
  int t = blockIdx.x * 4 + wave;
  const float* xr = x + (size_t)t * DDIM;
  float xv[16];
#pragma unroll
  for (int i = 0; i < 16; i += 4) *(float4*)&xv[i] = *(const float4*)&xr[lane * 16 + i];
  float acc[11];
#pragma unroll
  for (int j = 0; j < 11; ++j) {
    const float* w = (j < 3) ? (rW + j * DDIM) : (mW + (j - 3) * DDIM);
    float s = 0.f;
#pragma unroll
    for (int i = 0; i < 16; i += 4) {
      float4 wv = *(const float4*)&w[lane * 16 + i];
      s += xv[i] * wv.x + xv[i + 1] * wv.y + xv[i + 2] * wv.z + xv[i + 3] * wv.w;
    }
    acc[j] = s;
  }
#pragma unroll
  for (int j = 0; j < 11; ++j)
    for (int off = 32; off; off >>= 1) acc[j] += __shfl_xor(acc[j], off);
  if (lane == 0) {
    float l0 = acc[0] + rb[0], l1 = acc[1] + rb[1], l2 = acc[2] + rb[2];
    float mx = fmaxf(l0, fmaxf(l1, l2));
    float e0 = expf(l0 - mx), e1 = expf(l1 - mx), e2 = expf(l2 - mx);
    float inv = 1.f / (e0 + e1 + e2);
    float w2 = e2 * inv;
    bw3[t * 3 + 0] = e0 * inv; bw3[t * 3 + 1] = e1 * inv; bw3[t * 3 + 2] = w2;
    float lg[8];
#pragma unroll
    for (int e = 0; e < 8; ++e) lg[e] = acc[3 + e] + mb[e];
    int i0 = 0;
#pragma unroll
    for (int e = 1; e < 8; ++e) if (lg[e] > lg[i0]) i0 = e;
    int i1 = -1;
#pragma unroll
    for (int e = 0; e < 8; ++e) {
      if (e == i0) continue;
      if (i1 < 0 || lg[e] > lg[i1]) i1 = e;
    }
    float ee = expf(lg[i1] - lg[i0]);
    float w0 = 1.f / (1.f + ee), w1 = ee / (1.f + ee);
#pragma unroll
    for (int e = 0; e < 8; ++e) comb[t * 8 + e] = 0.f;
    comb[t * 8 + i0] = w2 * w0;
    comb[t * 8 + i1] = w2 * w1;
  }
}

// =======================================================================
// Double-buffered GEMM, co-residency-first: C[M,N] = A[M,K] @ B[N,K]^T.
// BK=32, 512 thr = 8 waves (2Mx4N). Tile BM_xBN_:
//   256x256: LDS 2x32KB = 64 KB -> 2 blocks/CU co-resident
//   128x128: LDS 2x16KB = 32 KB -> up to 4 blocks/CU
// Per tile: vmcnt(0) [own stage(t) loads done] + s_barrier [everyone's
// done]; read frags; stage(t+1); MFMA. WAR-safe with ONE barrier/tile:
// each wave's ds_reads are consumed by its MFMAs (lgkmcnt) before it can
// reach the next barrier, so buffer (t+1)&1 has no live readers when
// overwritten. Full-drain stalls are covered by the sibling block(s) on
// the CU (m97/m114 regime).
// LDS rows = 64B (4 slots of 16B); slot' = hi ^ ((row>>1)&3): within each
// consecutive-8-lane octet all (row-parity, slot) pairs distinct -> <=2-way
// bank aliasing (free). Pre-swizzled GLOBAL source + same XOR on read
// (global_load_lds dest stays linear).
// =======================================================================
DEV_INLINE void gload16(const bf16_t* g, bf16_t* l) {
  __builtin_amdgcn_global_load_lds((const __attribute__((address_space(1))) void*)g,
                                   (__attribute__((address_space(3))) void*)l, 16, 0, 0);
}

constexpr int EPI_BF16 = 0;   // Cb = bf16(v + bias[col])
constexpr int EPI_OUT_W = 1;  // Cf = scale[row]*(v+bias)
constexpr int EPI_OUT_A = 2;  // Cf += scale[row]*(v+bias)
constexpr int EPI_OUT_T = 3;  // atomicAdd(Cf, scale[row]*(v+bias)), skip scale==0
constexpr int EPI_SWIG  = 4;  // Cb = bf16(silu(v+bias)*aux[row,col])

template <int BM_, int BN_, int EPI>
__global__ __launch_bounds__(512, 4) void k_gemm8(
    const bf16_t* __restrict__ A, const bf16_t* __restrict__ B,
    bf16_t* __restrict__ Cb, float* __restrict__ Cf,
    const float* __restrict__ bias, const float* __restrict__ scale, int sstride,
    const bf16_t* __restrict__ aux, int ldaux,
    int N, int K,
    size_t zA, size_t zB, size_t zC, size_t zbias, size_t zaux, size_t zscale) {
  constexpr int NF = BN_ / 64;              // C col-frags per wave
  constexpr int MQ = BM_ / 128;             // 64-row quads per wave
  constexpr int MF = 4 * MQ;                // C row-frags per wave
  constexpr int ABYTES = BM_ * 64;          // A region bytes (BK=32)
  constexpr int BUF = (BM_ + BN_) * 64;     // bytes per LDS buffer
  __shared__ __align__(16) char lds[2 * BUF];

  const int tid = threadIdx.x;
  const int lane = tid & 63;
  const int wave = tid >> 6;
  const int lr = lane & 15;
  const int hi = lane >> 4;

  // bijective XCD-aware block swizzle (all grids here are %8==0)
  const int nbx = gridDim.x, nby = gridDim.y;
  int id = blockIdx.x + nbx * (blockIdx.y + nby * blockIdx.z);
  const int nwg = nbx * nby * (int)gridDim.z;
  if ((nwg & 7) == 0) id = (id & 7) * (nwg >> 3) + (id >> 3);
  const int bx = id % nbx;
  const int by = (id / nbx) % nby;
  const int bz = id / (nbx * nby);

  const int bm = by * BM_;
  const int bn = bx * BN_;
  const int wm = (wave >> 2) * (BM_ / 2);
  const int wn = (wave & 3) * (BN_ / 4);

  const bf16_t* Ab = A + (size_t)bz * zA;
  const bf16_t* Bb = B + (size_t)bz * zB + (size_t)bn * K;

  // staging: linear LDS slot `tid` of a region; slot s' of row r carries
  // global col-block s = s' ^ ((r>>1)&3)  (8 bf16 per block)
  const int srow = tid >> 2;                       // 0..127
  const int scol = 8 * ((tid & 3) ^ ((tid >> 3) & 3));
  const bf16_t* Asrc = Ab + (size_t)(bm + srow) * K + scol;
  const bf16_t* Bsrc = Bb + (size_t)srow * K + scol;
  const size_t r128K = (size_t)128 * K;
  const int NT = K >> 5;                           // BK = 32

  f32x4 acc[MF][NF];
#pragma unroll
  for (int a = 0; a < MF; ++a)
#pragma unroll
    for (int b = 0; b < NF; ++b)
#pragma unroll
      for (int j = 0; j < 4; ++j) acc[a][b][j] = 0.f;

  auto stageA = [&](int t) {
    const bf16_t* g = Asrc + (size_t)t * 32;
    char* l = lds + (t & 1) * BUF + tid * 16;
#pragma unroll
    for (int q = 0; q < MQ; ++q)
      gload16(g + (size_t)q * r128K, (bf16_t*)(l + q * 8192));
  };
  auto stageB = [&](int t) {
    const bf16_t* g = Bsrc + (size_t)t * 32;
    char* l = lds + (t & 1) * BUF + ABYTES + tid * 16;
#pragma unroll
    for (int q = 0; q < BN_ / 128; ++q)
      gload16(g + (size_t)q * r128K, (bf16_t*)(l + q * 8192));
  };
  auto rdA = [&](int buf, int row) -> bf16x8 {
    int off = buf + (row << 6) + ((hi ^ ((row >> 1) & 3)) << 4);
    return *(const bf16x8*)(lds + off);
  };
  auto rdB = [&](int buf, int row) -> bf16x8 {
    int off = buf + ABYTES + (row << 6) + ((hi ^ ((row >> 1) & 3)) << 4);
    return *(const bf16x8*)(lds + off);
  };

  auto tilebody = [&](int t, bool dostage) {
    const int buf = (t & 1) * BUF;
    bf16x8 bfr[NF], afr[4];
#pragma unroll
    for (int ni = 0; ni < NF; ++ni) bfr[ni] = rdB(buf, wn + ni * 16 + lr);
#pragma unroll
    for (int i = 0; i < 4; ++i) afr[i] = rdA(buf, wm + i * 16 + lr);
    if (dostage) {
      stageA(t + 1);
      if constexpr (MQ == 1) stageB(t + 1);
    }
    __builtin_amdgcn_s_setprio(1);
#pragma unroll
    for (int i = 0; i < 4; ++i)
#pragma unroll
      for (int ni = 0; ni < NF; ++ni)
        acc[i][ni] = __builtin_amdgcn_mfma_f32_16x16x32_bf16(afr[i], bfr[ni], acc[i][ni], 0, 0, 0);
    __builtin_amdgcn_s_setprio(0);
    if constexpr (MQ == 2) {
#pragma unroll
      for (int i = 0; i < 4; ++i) afr[i] = rdA(buf, wm + 64 + i * 16 + lr);
      if (dostage) stageB(t + 1);
      __builtin_amdgcn_s_setprio(1);
#pragma unroll
      for (int i = 0; i < 4; ++i)
#pragma unroll
        for (int ni = 0; ni < NF; ++ni)
          acc[4 + i][ni] = __builtin_amdgcn_mfma_f32_16x16x32_bf16(afr[i], bfr[ni], acc[4 + i][ni], 0, 0, 0);
      __builtin_amdgcn_s_setprio(0);
    }
  };

  // prologue: stage tile 0
  stageA(0); stageB(0);

  for (int t = 0; t < NT; ++t) {
    VMCNT(0);
    BARF();
    tilebody(t, t + 1 < NT);
  }

  // ---------------- epilogue ----------------
  const float* bp = bias + bz * zbias;
  const float* sp = scale ? scale + bz * zscale : nullptr;
  const bf16_t* ap = aux ? aux + bz * zaux : nullptr;
  bf16_t* cbp = Cb ? Cb + bz * zC : nullptr;
  float* cfp = Cf;
  float bv[NF];
#pragma unroll
  for (int ni = 0; ni < NF; ++ni) bv[ni] = bp[bn + wn + ni * 16 + lr];
#pragma unroll
  for (int mi = 0; mi < MF; ++mi) {
#pragma unroll
    for (int j = 0; j < 4; ++j) {
      const int rowg = bm + wm + mi * 16 + hi * 4 + j;
      float sc = 0.f;
      if constexpr (EPI == EPI_OUT_W || EPI == EPI_OUT_A || EPI == EPI_OUT_T)
        sc = sp[(size_t)rowg * sstride];
      bool go = true;
      if constexpr (EPI == EPI_OUT_T) go = (sc != 0.f);
      if (go) {
#pragma unroll
        for (int ni = 0; ni < NF; ++ni) {
          const int colg = bn + wn + ni * 16 + lr;
          float v = acc[mi][ni][j] + bv[ni];
          if constexpr (EPI == EPI_BF16) {
            cbp[(size_t)rowg * N + colg] = (bf16_t)v;
          } else if constexpr (EPI == EPI_OUT_W) {
            cfp[(size_t)rowg * N + colg] = sc * v;
          } else if constexpr (EPI == EPI_OUT_A) {
            cfp[(size_t)rowg * N + colg] += sc * v;
          } else if constexpr (EPI == EPI_OUT_T) {
            atomicAdd(&cfp[(size_t)rowg * N + colg], sc * v);
          } else {
            float bb = (float)ap[(size_t)rowg * ldaux + colg];
            float s = v / (1.f + __expf(-v));
            cbp[(size_t)rowg * N + colg] = (bf16_t)(s * bb);
          }
        }
      }
    }
  }
}

// ---------------------------------------------------------------------------
extern "C" void kernel_launch(void* const* d_in, const int* in_sizes, int n_in,
                              void* d_out, int out_size, void* d_ws, size_t ws_size,
                              hipStream_t stream) {
  (void)in_sizes; (void)n_in; (void)out_size; (void)ws_size;
  const float* x    = (const float*)d_in[0];
  const float* rW   = (const float*)d_in[1];
  const float* rb   = (const float*)d_in[2];
  const float* d1W  = (const float*)d_in[3];
  const float* d1b  = (const float*)d_in[4];
  const float* d2W  = (const float*)d_in[5];
  const float* d2b  = (const float*)d_in[6];
  const float* sWin = (const float*)d_in[7];
  const float* sbin = (const float*)d_in[8];
  const float* sWc  = (const float*)d_in[9];
  const float* sbc  = (const float*)d_in[10];
  const float* sWo  = (const float*)d_in[11];
  const float* sbo  = (const float*)d_in[12];
  const float* mW   = (const float*)d_in[13];
  const float* mb   = (const float*)d_in[14];
  const float* eW1  = (const float*)d_in[15];
  const float* eb1  = (const float*)d_in[16];
  const float* eW2  = (const float*)d_in[17];
  const float* eb2  = (const float*)d_in[18];
  float* out = (float*)d_out;

  char* ws = (char*)d_ws;
  size_t off = 0;
  auto alloc = [&](size_t bytes) -> void* {
    void* p = ws + off;
    off += (bytes + 255) & ~(size_t)255;
    return p;
  };
  bf16_t* xb    = (bf16_t*)alloc((size_t)NTOK * DDIM * 2);
  bf16_t* wd1   = (bf16_t*)alloc((size_t)2 * HDIM * DDIM * 2);
  bf16_t* wd2   = (bf16_t*)alloc((size_t)DDIM * HDIM * 2);
  bf16_t* wsin  = (bf16_t*)alloc((size_t)SDIM * DDIM * 2);
  bf16_t* wconv = (bf16_t*)alloc((size_t)SDIM * SDIM * 4 * 2);
  bf16_t* wsout = (bf16_t*)alloc((size_t)DDIM * SDIM * 2);
  bf16_t* we1   = (bf16_t*)alloc((size_t)NEXP * 2 * HEXP * DDIM * 2);
  bf16_t* we2   = (bf16_t*)alloc((size_t)NEXP * DDIM * HEXP * 2);
  bf16_t* Cc    = (bf16_t*)alloc((size_t)NTOK * HDIM * 2);  // fc1-a/swiglu out | MoE swiglu out
  bf16_t* Dd    = (bf16_t*)alloc((size_t)NTOK * HDIM * 2);  // fc1-b | MoE fc1-b | im2col
  bf16_t* th    = (bf16_t*)alloc((size_t)NTOK * SDIM * 2);
  bf16_t* tsq   = (bf16_t*)alloc((size_t)NTOK * SDIM * 2);
  float*  bw3   = (float*)alloc((size_t)NTOK * 3 * 4);
  float*  comb  = (float*)alloc((size_t)NTOK * NEXP * 4);

  // conversions + router
  k_f32_to_bf16<<<4096, 256, 0, stream>>>(x, xb, NTOK * DDIM / 8);
  k_f32_to_bf16<<<4096, 256, 0, stream>>>(d1W, wd1, 2 * HDIM * DDIM / 8);
  k_f32_to_bf16<<<2048, 256, 0, stream>>>(d2W, wd2, DDIM * HDIM / 8);
  k_f32_to_bf16<<<512, 256, 0, stream>>>(sWin, wsin, SDIM * DDIM / 8);
  k_convw<<<2048, 256, 0, stream>>>(sWc, wconv);
  k_f32_to_bf16<<<512, 256, 0, stream>>>(sWo, wsout, DDIM * SDIM / 8);
  k_f32_to_bf16<<<4096, 256, 0, stream>>>(eW1, we1, NEXP * 2 * HEXP * DDIM / 8);
  k_f32_to_bf16<<<2048, 256, 0, stream>>>(eW2, we2, NEXP * DDIM * HEXP / 8);
  k_router<<<2048, 256, 0, stream>>>(x, rW, rb, mW, mb, bw3, comb);

  // ---- dense branch: fc1-b, fc1-a(+fused swiglu), d2 -> out ----
  k_gemm8<256, 256, EPI_BF16><<<dim3(16, 32, 1), 512, 0, stream>>>(
      xb, wd1 + (size_t)HDIM * DDIM, Dd, nullptr, d1b + HDIM, nullptr, 0, nullptr, 0,
      HDIM, DDIM, 0, 0, 0, 0, 0, 0);
  k_gemm8<256, 256, EPI_SWIG><<<dim3(16, 32, 1), 512, 0, stream>>>(
      xb, wd1, Cc, nullptr, d1b, nullptr, 0, Dd, HDIM,
      HDIM, DDIM, 0, 0, 0, 0, 0, 0);
  k_gemm8<128, 128, EPI_OUT_W><<<dim3(8, 64, 1), 512, 0, stream>>>(
      Cc, wd2, nullptr, out, d2b, bw3, 3, nullptr, 0,
      DDIM, HDIM, 0, 0, 0, 0, 0, 0);

  // ---- MoE (dense dispatch, batched over z; combine pre-scaled by bw2) ----
  k_gemm8<128, 128, EPI_BF16><<<dim3(4, 64, 8), 512, 0, stream>>>(
      xb, we1 + (size_t)HEXP * DDIM, Dd, nullptr, eb1 + HEXP, nullptr, 0, nullptr, 0,
      HEXP, DDIM, 0, (size_t)2 * HEXP * DDIM, (size_t)NTOK * HEXP, 2 * HEXP, 0, 0);
  k_gemm8<128, 128, EPI_SWIG><<<dim3(4, 64, 8), 512, 0, stream>>>(
      xb, we1, Cc, nullptr, eb1, nullptr, 0, Dd, HEXP,
      HEXP, DDIM, 0, (size_t)2 * HEXP * DDIM, (size_t)NTOK * HEXP, 2 * HEXP,
      (size_t)NTOK * HEXP, 0);
  k_gemm8<128, 128, EPI_OUT_T><<<dim3(8, 64, 8), 512, 0, stream>>>(
      Cc, we2, nullptr, out, eb2, comb, NEXP, nullptr, 0,
      DDIM, HEXP, (size_t)NTOK * HEXP, (size_t)DDIM * HEXP, 0, DDIM, 0, 1);

  // ---- SSM branch ----
  k_gemm8<128, 128, EPI_BF16><<<dim3(8, 64, 1), 512, 0, stream>>>(
      xb, wsin, th, nullptr, sbin, nullptr, 0, nullptr, 0,
      SDIM, DDIM, 0, 0, 0, 0, 0, 0);
  k_im2col<<<16384, 256, 0, stream>>>(th, Dd);
  k_gemm8<128, 128, EPI_BF16><<<dim3(8, 64, 1), 512, 0, stream>>>(
      Dd, wconv, tsq, nullptr, sbc, nullptr, 0, nullptr, 0,
      SDIM, SDIM * 4, 0, 0, 0, 0, 0, 0);
  k_gemm8<128, 128, EPI_OUT_A><<<dim3(8, 64, 1), 512, 0, stream>>>(
      tsq, wsout, nullptr, out, sbo, bw3 + 1, 3, nullptr, 0,
      DDIM, SDIM, 0, 0, 0, 0, 0, 0);
}

// Round 7
// 872.636 us; speedup vs baseline: 2.0786x; 2.0786x over previous
//
#include <hip/hip_runtime.h>
#include <hip/hip_bf16.h>
#include <cstdint>

typedef __bf16 bf16_t;
typedef __bf16 bf16x8 __attribute__((ext_vector_type(8)));
typedef float f32x4 __attribute__((ext_vector_type(4)));

#define DEV_INLINE __device__ __forceinline__

#define NTOK 8192
#define DDIM 1024
#define HDIM 4096
#define SDIM 1024
#define NEXP 8
#define HEXP 512
#define TSEQ 2048
#define MAXTILES 136
#define MAXROWS (MAXTILES * 128)

#define VMCNT(n) asm volatile("s_waitcnt vmcnt(" #n ")" ::: "memory")
#define BARF() asm volatile("s_barrier" ::: "memory")

// ---------------- conversion: f32 -> bf16, 8 elems/thread ----------------
__global__ __launch_bounds__(256) void k_f32_to_bf16(const float* __restrict__ src,
                                                     bf16_t* __restrict__ dst, int n8) {
  int i = blockIdx.x * 256 + threadIdx.x;
  if (i >= n8) return;
  const float4* s = (const float4*)src + (size_t)i * 2;
  float4 v0 = s[0], v1 = s[1];
  bf16x8 o;
  o[0] = (bf16_t)v0.x; o[1] = (bf16_t)v0.y; o[2] = (bf16_t)v0.z; o[3] = (bf16_t)v0.w;
  o[4] = (bf16_t)v1.x; o[5] = (bf16_t)v1.y; o[6] = (bf16_t)v1.z; o[7] = (bf16_t)v1.w;
  *((bf16x8*)dst + i) = o;
}

// ------------- conv weight: [S][S][K] f32 -> [S][K*S] bf16 (k-major) -------------
__global__ __launch_bounds__(256) void k_convw(const float* __restrict__ src,
                                               bf16_t* __restrict__ dst) {
  int i = blockIdx.x * 256 + threadIdx.x;
  size_t flat = (size_t)i * 8;
  int s = (int)(flat >> 12);
  int col = (int)(flat & 4095);
  int k = col >> 10;
  int si0 = col & 1023;
  const float* sp = src + (size_t)s * 4096 + k;
  bf16x8 o;
#pragma unroll
  for (int j = 0; j < 8; ++j) o[j] = (bf16_t)sp[(size_t)(si0 + j) * 4];
  *(bf16x8*)(dst + flat) = o;
}

// ------------- im2col: h[8192][1024] -> A2[8192][4096] -------------
__global__ __launch_bounds__(256) void k_im2col(const bf16_t* __restrict__ h,
                                                bf16_t* __restrict__ a2) {
  int i = blockIdx.x * 256 + threadIdx.x;
  size_t flat = (size_t)i * 8;
  int t = (int)(flat >> 12);
  int col = (int)(flat & 4095);
  int k = col >> 10;
  int si = col & 1023;
  int tt = t & (TSEQ - 1);
  bf16x8 v;
#pragma unroll
  for (int j = 0; j < 8; ++j) v[j] = (bf16_t)0.f;
  if (tt - 3 + k >= 0) v = *(const bf16x8*)(h + (size_t)(t - 3 + k) * SDIM + si);
  *(bf16x8*)(a2 + flat) = v;
}

// ------------- MoE bookkeeping -------------
__global__ __launch_bounds__(256) void k_zero(int* cnt, int* fill, int* idx,
                                              float* gate) {
  int i = blockIdx.x * 256 + threadIdx.x;
  if (i < NEXP) { cnt[i] = 0; fill[i] = 0; }
  if (i < MAXROWS) { idx[i] = 0; gate[i] = 0.f; }
}

__global__ void k_scan(const int* __restrict__ cnt, int* __restrict__ base,
                       int* __restrict__ ntiles, int* __restrict__ tile_e,
                       int* __restrict__ tile_row) {
  if (threadIdx.x == 0 && blockIdx.x == 0) {
    int b = 0, tt = 0;
    for (int e = 0; e < NEXP; ++e) {
      base[e] = b;
      int nt = (cnt[e] + 127) >> 7;
      for (int j = 0; j < nt; ++j) { tile_e[tt] = e; tile_row[tt] = b + j * 128; ++tt; }
      b += nt * 128;
    }
    *ntiles = tt;
  }
}

__global__ __launch_bounds__(256) void k_scatter(const int* __restrict__ top2e,
                                                 const float* __restrict__ top2w,
                                                 const int* __restrict__ base,
                                                 int* __restrict__ fill,
                                                 int* __restrict__ idx,
                                                 float* __restrict__ gate) {
  int t = blockIdx.x * 256 + threadIdx.x;
#pragma unroll
  for (int j = 0; j < 2; ++j) {
    int e = top2e[t * 2 + j];
    int slot = atomicAdd(&fill[e], 1);
    int p = base[e] + slot;
    idx[p] = t;
    gate[p] = top2w[t * 2 + j];
  }
}

// ------------- router: branch softmax [8192,3] + MoE top-2 (ids, w2-scaled weights) -------------
__global__ __launch_bounds__(256) void k_router(const float* __restrict__ x,
                                                const float* __restrict__ rW,
                                                const float* __restrict__ rb,
                                                const float* __restrict__ mW,
                                                const float* __restrict__ mb,
                                                float* __restrict__ bw3,
                                                int* __restrict__ top2e,
                                                float* __restrict__ top2w,
                                                int* __restrict__ cnt) {
  int wave = threadIdx.x >> 6, lane = threadIdx.x & 63;
  int t = blockIdx.x * 4 + wave;
  const float* xr = x + (size_t)t * DDIM;
  float xv[16];
#pragma unroll
  for (int i = 0; i < 16; i += 4) *(float4*)&xv[i] = *(const float4*)&xr[lane * 16 + i];
  float acc[11];
#pragma unroll
  for (int j = 0; j < 11; ++j) {
    const float* w = (j < 3) ? (rW + j * DDIM) : (mW + (j - 3) * DDIM);
    float s = 0.f;
#pragma unroll
    for (int i = 0; i < 16; i += 4) {
      float4 wv = *(const float4*)&w[lane * 16 + i];
      s += xv[i] * wv.x + xv[i + 1] * wv.y + xv[i + 2] * wv.z + xv[i + 3] * wv.w;
    }
    acc[j] = s;
  }
#pragma unroll
  for (int j = 0; j < 11; ++j)
    for (int off = 32; off; off >>= 1) acc[j] += __shfl_xor(acc[j], off);
  if (lane == 0) {
    float l0 = acc[0] + rb[0], l1 = acc[1] + rb[1], l2 = acc[2] + rb[2];
    float mx = fmaxf(l0, fmaxf(l1, l2));
    float e0 = expf(l0 - mx), e1 = expf(l1 - mx), e2 = expf(l2 - mx);
    float inv = 1.f / (e0 + e1 + e2);
    float w2 = e2 * inv;
    bw3[t * 3 + 0] = e0 * inv; bw3[t * 3 + 1] = e1 * inv; bw3[t * 3 + 2] = w2;
    float lg[8];
#pragma unroll
    for (int e = 0; e < 8; ++e) lg[e] = acc[3 + e] + mb[e];
    int i0 = 0;
#pragma unroll
    for (int e = 1; e < 8; ++e) if (lg[e] > lg[i0]) i0 = e;
    int i1 = -1;
#pragma unroll
    for (int e = 0; e < 8; ++e) {
      if (e == i0) continue;
      if (i1 < 0 || lg[e] > lg[i1]) i1 = e;
    }
    float ee = expf(lg[i1] - lg[i0]);
    float w0 = 1.f / (1.f + ee), w1 = ee / (1.f + ee);
    top2e[t * 2 + 0] = i0; top2e[t * 2 + 1] = i1;
    top2w[t * 2 + 0] = w2 * w0; top2w[t * 2 + 1] = w2 * w1;
    atomicAdd(&cnt[i0], 1); atomicAdd(&cnt[i1], 1);
  }
}

// =======================================================================
// Dense GEMM (round-5 proven): C[M=8192,N] = A[M,K] @ B[N,K]^T, bf16.
// BM=256, BK=32, 512 thr = 8 waves (2Mx4N). Quad-buffered, tile t+3 staged
// during t, uniform counted vmcnt (never 0 in loop), conflict-free swizzle
// slot' = hi ^ ((row>>1)&3) via pre-swizzled global source + XOR on read.
// =======================================================================
DEV_INLINE void gload16(const bf16_t* g, bf16_t* l) {
  __builtin_amdgcn_global_load_lds((const __attribute__((address_space(1))) void*)g,
                                   (__attribute__((address_space(3))) void*)l, 16, 0, 0);
}

constexpr int EPI_BF16 = 0;   // Cb = bf16(v + bias[col])
constexpr int EPI_OUT_W = 1;  // Cf = scale[row]*(v+bias)
constexpr int EPI_OUT_A = 2;  // Cf += scale[row]*(v+bias)
constexpr int EPI_SWIG = 4;   // Cb = bf16(silu(v+bias)*aux[row,col])
constexpr int EPI_SCAT = 5;   // atomicAdd(Cf[token], gate*(v+bias)) [MoE fc2]

template <int BN_, int EPI>
__global__ __launch_bounds__(512, 2) void k_gemm8(
    const bf16_t* __restrict__ A, const bf16_t* __restrict__ B,
    bf16_t* __restrict__ Cb, float* __restrict__ Cf,
    const float* __restrict__ bias, const float* __restrict__ scale, int sstride,
    const bf16_t* __restrict__ aux, int ldaux,
    int N, int K) {
  constexpr int NF = BN_ / 64;
  constexpr int BUF = 16384 + BN_ * 64;
  __shared__ __align__(16) char lds[4 * BUF];

  const int tid = threadIdx.x;
  const int lane = tid & 63;
  const int wave = tid >> 6;
  const int lr = lane & 15;
  const int hi = lane >> 4;

  const int nbx = gridDim.x, nby = gridDim.y;
  int id = blockIdx.x + nbx * blockIdx.y;
  const int nwg = nbx * nby;
  if ((nwg & 7) == 0) id = (id & 7) * (nwg >> 3) + (id >> 3);
  const int bx = id % nbx;
  const int by = id / nbx;

  const int bm = by * 256;
  const int bn = bx * BN_;
  const int wm = (wave >> 2) * 128;
  const int wn = (wave & 3) * (BN_ / 4);

  const bf16_t* Bb = B + (size_t)bn * K;

  const int srow = tid >> 2;
  const int scol = 8 * ((tid & 3) ^ ((tid >> 3) & 3));
  const bf16_t* Asrc = A + (size_t)(bm + srow) * K + scol;
  const bf16_t* Bsrc = Bb + (size_t)srow * K + scol;
  const size_t r128K = (size_t)128 * K;
  const int NT = K >> 5;

  f32x4 acc[8][NF];
#pragma unroll
  for (int a = 0; a < 8; ++a)
#pragma unroll
    for (int b = 0; b < NF; ++b)
#pragma unroll
      for (int j = 0; j < 4; ++j) acc[a][b][j] = 0.f;

  auto stageA = [&](int t) {
    const bf16_t* g = Asrc + (size_t)t * 32;
    char* l = lds + (t & 3) * BUF + tid * 16;
    gload16(g, (bf16_t*)l);
    gload16(g + r128K, (bf16_t*)(l + 8192));
  };
  auto stageB = [&](int t) {
    const bf16_t* g = Bsrc + (size_t)t * 32;
    char* l = lds + (t & 3) * BUF + 16384 + tid * 16;
    gload16(g, (bf16_t*)l);
    if constexpr (BN_ == 256) gload16(g + r128K, (bf16_t*)(l + 8192));
  };
  auto rdA = [&](int buf, int row) -> bf16x8 {
    int off = buf + (row << 6) + ((hi ^ ((row >> 1) & 3)) << 4);
    return *(const bf16x8*)(lds + off);
  };
  auto rdB = [&](int buf, int row) -> bf16x8 {
    int off = buf + 16384 + (row << 6) + ((hi ^ ((row >> 1) & 3)) << 4);
    return *(const bf16x8*)(lds + off);
  };

  auto tilebody = [&](int t, bool dostage) {
    const int buf = (t & 3) * BUF;
    bf16x8 bfr[NF], afr[4];
#pragma unroll
    for (int ni = 0; ni < NF; ++ni) bfr[ni] = rdB(buf, wn + ni * 16 + lr);
#pragma unroll
    for (int i = 0; i < 4; ++i) afr[i] = rdA(buf, wm + i * 16 + lr);
    if (dostage) stageA(t + 3);
    __builtin_amdgcn_s_setprio(1);
#pragma unroll
    for (int i = 0; i < 4; ++i)
#pragma unroll
      for (int ni = 0; ni < NF; ++ni)
        acc[i][ni] = __builtin_amdgcn_mfma_f32_16x16x32_bf16(afr[i], bfr[ni], acc[i][ni], 0, 0, 0);
    __builtin_amdgcn_s_setprio(0);
#pragma unroll
    for (int i = 0; i < 4; ++i) afr[i] = rdA(buf, wm + 64 + i * 16 + lr);
    if (dostage) stageB(t + 3);
    __builtin_amdgcn_s_setprio(1);
#pragma unroll
    for (int i = 0; i < 4; ++i)
#pragma unroll
      for (int ni = 0; ni < NF; ++ni)
        acc[4 + i][ni] = __builtin_amdgcn_mfma_f32_16x16x32_bf16(afr[i], bfr[ni], acc[4 + i][ni], 0, 0, 0);
    __builtin_amdgcn_s_setprio(0);
  };

  stageA(0); stageB(0); stageA(1); stageB(1); stageA(2); stageB(2);

  for (int t = 0; t < NT - 3; ++t) {
    if constexpr (BN_ == 256) { VMCNT(8); } else { VMCNT(6); }
    BARF();
    tilebody(t, true);
  }
  if constexpr (BN_ == 256) { VMCNT(8); } else { VMCNT(6); }
  BARF();
  tilebody(NT - 3, false);
  if constexpr (BN_ == 256) { VMCNT(4); } else { VMCNT(3); }
  BARF();
  tilebody(NT - 2, false);
  VMCNT(0);
  BARF();
  tilebody(NT - 1, false);

  float bv[NF];
#pragma unroll
  for (int ni = 0; ni < NF; ++ni) bv[ni] = bias[bn + wn + ni * 16 + lr];
#pragma unroll
  for (int mi = 0; mi < 8; ++mi) {
#pragma unroll
    for (int j = 0; j < 4; ++j) {
      const int rowg = bm + wm + mi * 16 + hi * 4 + j;
      float sc = 0.f;
      if constexpr (EPI == EPI_OUT_W || EPI == EPI_OUT_A)
        sc = scale[(size_t)rowg * sstride];
#pragma unroll
      for (int ni = 0; ni < NF; ++ni) {
        const int colg = bn + wn + ni * 16 + lr;
        float v = acc[mi][ni][j] + bv[ni];
        if constexpr (EPI == EPI_BF16) {
          Cb[(size_t)rowg * N + colg] = (bf16_t)v;
        } else if constexpr (EPI == EPI_OUT_W) {
          Cf[(size_t)rowg * N + colg] = sc * v;
        } else if constexpr (EPI == EPI_OUT_A) {
          Cf[(size_t)rowg * N + colg] += sc * v;
        } else {
          float bb = (float)aux[(size_t)rowg * ldaux + colg];
          float s = v / (1.f + __expf(-v));
          Cb[(size_t)rowg * N + colg] = (bf16_t)(s * bb);
        }
      }
    }
  }
}

// =======================================================================
// Sparse MoE GEMM: tile-descriptor driven, BM=BN=128, 8 waves (2Mx4N),
// quad-buffered BK=32 (2 loads/tile -> gate vmcnt(4), peel 4/2/0).
// GA: A rows gathered via idx[] (fc1, A=xb); else slot-linear (fc2, A=Cc).
// EPI_SCAT scatters to out[token] via atomicAdd with per-row gate.
// =======================================================================
template <int EPI, bool GA>
__global__ __launch_bounds__(512, 2) void k_moe_gemm(
    const bf16_t* __restrict__ A, const bf16_t* __restrict__ Bw, size_t zB, int boff,
    bf16_t* __restrict__ Cb, float* __restrict__ Cf,
    const float* __restrict__ bias, int bstride,
    const bf16_t* __restrict__ aux,
    const int* __restrict__ ntiles_p, const int* __restrict__ tile_e,
    const int* __restrict__ tile_row, const int* __restrict__ idx,
    const float* __restrict__ gate,
    int N, int K) {
  constexpr int BUF = 16384;  // 128*64 (A) + 128*64 (B) bytes
  __shared__ __align__(16) char lds[4 * BUF];

  const int tid = threadIdx.x;
  const int lane = tid & 63;
  const int wave = tid >> 6;
  const int lr = lane & 15;
  const int hi = lane >> 4;

  const int nbx = gridDim.x, nby = gridDim.y;
  int id = blockIdx.x + nbx * blockIdx.y;
  const int nwg = nbx * nby;
  if ((nwg & 7) == 0) id = (id & 7) * (nwg >> 3) + (id >> 3);
  const int bx = id % nbx;
  const int by = id / nbx;

  const int ntiles = *ntiles_p;
  if (bx >= ntiles) return;
  const int e = tile_e[bx];
  const int bm = tile_row[bx];
  const int bn = by * 128;
  const int wm = (wave >> 2) * 64;
  const int wn = (wave & 3) * 32;

  const int srow = tid >> 2;
  const int scol = 8 * ((tid & 3) ^ ((tid >> 3) & 3));
  const int arow = bm + srow;
  const int atok = GA ? idx[arow] : arow;
  const bf16_t* Asrc = A + (size_t)atok * K + scol;
  const bf16_t* Bsrc = Bw + (size_t)e * zB + (size_t)(boff + bn + srow) * K + scol;
  const int NT = K >> 5;

  f32x4 acc[4][2];
#pragma unroll
  for (int a = 0; a < 4; ++a)
#pragma unroll
    for (int b = 0; b < 2; ++b)
#pragma unroll
      for (int j = 0; j < 4; ++j) acc[a][b][j] = 0.f;

  auto stage = [&](int t) {
    char* l = lds + (t & 3) * BUF + tid * 16;
    gload16(Asrc + (size_t)t * 32, (bf16_t*)l);
    gload16(Bsrc + (size_t)t * 32, (bf16_t*)(l + 8192));
  };
  auto rdA = [&](int buf, int row) -> bf16x8 {
    int off = buf + (row << 6) + ((hi ^ ((row >> 1) & 3)) << 4);
    return *(const bf16x8*)(lds + off);
  };
  auto rdB = [&](int buf, int row) -> bf16x8 {
    int off = buf + 8192 + (row << 6) + ((hi ^ ((row >> 1) & 3)) << 4);
    return *(const bf16x8*)(lds + off);
  };

  auto tilebody = [&](int t, bool dostage) {
    const int buf = (t & 3) * BUF;
    bf16x8 bfr[2], afr[4];
#pragma unroll
    for (int ni = 0; ni < 2; ++ni) bfr[ni] = rdB(buf, wn + ni * 16 + lr);
#pragma unroll
    for (int i = 0; i < 4; ++i) afr[i] = rdA(buf, wm + i * 16 + lr);
    if (dostage) stage(t + 3);
    __builtin_amdgcn_s_setprio(1);
#pragma unroll
    for (int i = 0; i < 4; ++i)
#pragma unroll
      for (int ni = 0; ni < 2; ++ni)
        acc[i][ni] = __builtin_amdgcn_mfma_f32_16x16x32_bf16(afr[i], bfr[ni], acc[i][ni], 0, 0, 0);
    __builtin_amdgcn_s_setprio(0);
  };

  stage(0); stage(1); stage(2);

  for (int t = 0; t < NT - 3; ++t) {
    VMCNT(4);
    BARF();
    tilebody(t, true);
  }
  VMCNT(4); BARF(); tilebody(NT - 3, false);
  VMCNT(2); BARF(); tilebody(NT - 2, false);
  VMCNT(0); BARF(); tilebody(NT - 1, false);

  const float* bp = bias + (size_t)e * bstride + boff;
  float bv[2];
#pragma unroll
  for (int ni = 0; ni < 2; ++ni) bv[ni] = bp[bn + wn + ni * 16 + lr];
#pragma unroll
  for (int mi = 0; mi < 4; ++mi) {
#pragma unroll
    for (int j = 0; j < 4; ++j) {
      const int slot = bm + wm + mi * 16 + hi * 4 + j;
      float sc = 0.f;
      int tok = 0;
      if constexpr (EPI == EPI_SCAT) { sc = gate[slot]; tok = idx[slot]; }
#pragma unroll
      for (int ni = 0; ni < 2; ++ni) {
        const int colg = bn + wn + ni * 16 + lr;
        float v = acc[mi][ni][j] + bv[ni];
        if constexpr (EPI == EPI_BF16) {
          Cb[(size_t)slot * N + colg] = (bf16_t)v;
        } else if constexpr (EPI == EPI_SWIG) {
          float bb = (float)aux[(size_t)slot * N + colg];
          float s = v / (1.f + __expf(-v));
          Cb[(size_t)slot * N + colg] = (bf16_t)(s * bb);
        } else {
          if (sc != 0.f) atomicAdd(&Cf[(size_t)tok * N + colg], sc * v);
        }
      }
    }
  }
}

// ---------------------------------------------------------------------------
extern "C" void kernel_launch(void* const* d_in, const int* in_sizes, int n_in,
                              void* d_out, int out_size, void* d_ws, size_t ws_size,
                              hipStream_t stream) {
  (void)in_sizes; (void)n_in; (void)out_size; (void)ws_size;
  const float* x    = (const float*)d_in[0];
  const float* rW   = (const float*)d_in[1];
  const float* rb   = (const float*)d_in[2];
  const float* d1W  = (const float*)d_in[3];
  const float* d1b  = (const float*)d_in[4];
  const float* d2W  = (const float*)d_in[5];
  const float* d2b  = (const float*)d_in[6];
  const float* sWin = (const float*)d_in[7];
  const float* sbin = (const float*)d_in[8];
  const float* sWc  = (const float*)d_in[9];
  const float* sbc  = (const float*)d_in[10];
  const float* sWo  = (const float*)d_in[11];
  const float* sbo  = (const float*)d_in[12];
  const float* mW   = (const float*)d_in[13];
  const float* mb   = (const float*)d_in[14];
  const float* eW1  = (const float*)d_in[15];
  const float* eb1  = (const float*)d_in[16];
  const float* eW2  = (const float*)d_in[17];
  const float* eb2  = (const float*)d_in[18];
  float* out = (float*)d_out;

  char* ws = (char*)d_ws;
  size_t off = 0;
  auto alloc = [&](size_t bytes) -> void* {
    void* p = ws + off;
    off += (bytes + 255) & ~(size_t)255;
    return p;
  };
  bf16_t* xb    = (bf16_t*)alloc((size_t)NTOK * DDIM * 2);
  bf16_t* wd1   = (bf16_t*)alloc((size_t)2 * HDIM * DDIM * 2);
  bf16_t* wd2   = (bf16_t*)alloc((size_t)DDIM * HDIM * 2);
  bf16_t* wsin  = (bf16_t*)alloc((size_t)SDIM * DDIM * 2);
  bf16_t* wconv = (bf16_t*)alloc((size_t)SDIM * SDIM * 4 * 2);
  bf16_t* wsout = (bf16_t*)alloc((size_t)DDIM * SDIM * 2);
  bf16_t* we1   = (bf16_t*)alloc((size_t)NEXP * 2 * HEXP * DDIM * 2);
  bf16_t* we2   = (bf16_t*)alloc((size_t)NEXP * DDIM * HEXP * 2);
  bf16_t* Cc    = (bf16_t*)alloc((size_t)NTOK * HDIM * 2);  // fc1-a/swiglu | MoE swiglu (slot)
  bf16_t* Dd    = (bf16_t*)alloc((size_t)NTOK * HDIM * 2);  // fc1-b | MoE fc1-b (slot) | im2col
  bf16_t* th    = (bf16_t*)alloc((size_t)NTOK * SDIM * 2);
  bf16_t* tsq   = (bf16_t*)alloc((size_t)NTOK * SDIM * 2);
  float*  bw3   = (float*)alloc((size_t)NTOK * 3 * 4);
  int*    top2e = (int*)alloc((size_t)NTOK * 2 * 4);
  float*  top2w = (float*)alloc((size_t)NTOK * 2 * 4);
  int*    cnt   = (int*)alloc(NEXP * 4);
  int*    fill  = (int*)alloc(NEXP * 4);
  int*    basep = (int*)alloc((NEXP + 1) * 4);
  int*    ntl   = (int*)alloc(4);
  int*    t_e   = (int*)alloc(MAXTILES * 4);
  int*    t_row = (int*)alloc(MAXTILES * 4);
  int*    idx   = (int*)alloc(MAXROWS * 4);
  float*  gate  = (float*)alloc(MAXROWS * 4);

  // conversions + router + MoE bookkeeping
  k_f32_to_bf16<<<4096, 256, 0, stream>>>(x, xb, NTOK * DDIM / 8);
  k_f32_to_bf16<<<4096, 256, 0, stream>>>(d1W, wd1, 2 * HDIM * DDIM / 8);
  k_f32_to_bf16<<<2048, 256, 0, stream>>>(d2W, wd2, DDIM * HDIM / 8);
  k_f32_to_bf16<<<512, 256, 0, stream>>>(sWin, wsin, SDIM * DDIM / 8);
  k_convw<<<2048, 256, 0, stream>>>(sWc, wconv);
  k_f32_to_bf16<<<512, 256, 0, stream>>>(sWo, wsout, DDIM * SDIM / 8);
  k_f32_to_bf16<<<4096, 256, 0, stream>>>(eW1, we1, NEXP * 2 * HEXP * DDIM / 8);
  k_f32_to_bf16<<<2048, 256, 0, stream>>>(eW2, we2, NEXP * DDIM * HEXP / 8);
  k_zero<<<(MAXROWS + 255) / 256, 256, 0, stream>>>(cnt, fill, idx, gate);
  k_router<<<2048, 256, 0, stream>>>(x, rW, rb, mW, mb, bw3, top2e, top2w, cnt);
  k_scan<<<1, 64, 0, stream>>>(cnt, basep, ntl, t_e, t_row);
  k_scatter<<<NTOK / 256, 256, 0, stream>>>(top2e, top2w, basep, fill, idx, gate);

  // ---- dense branch: fc1-b, fc1-a(+fused swiglu), d2 -> out ----
  k_gemm8<256, EPI_BF16><<<dim3(16, 32), 512, 0, stream>>>(
      xb, wd1 + (size_t)HDIM * DDIM, Dd, nullptr, d1b + HDIM, nullptr, 0, nullptr, 0,
      HDIM, DDIM);
  k_gemm8<256, EPI_SWIG><<<dim3(16, 32), 512, 0, stream>>>(
      xb, wd1, Cc, nullptr, d1b, nullptr, 0, Dd, HDIM, HDIM, DDIM);
  k_gemm8<128, EPI_OUT_W><<<dim3(8, 32), 512, 0, stream>>>(
      Cc, wd2, nullptr, out, d2b, bw3, 3, nullptr, 0, DDIM, HDIM);

  // ---- sparse MoE: gathered fc1-b, fc1-a(+swiglu), fc2 scatter ----
  k_moe_gemm<EPI_BF16, true><<<dim3(MAXTILES, 4), 512, 0, stream>>>(
      xb, we1, (size_t)2 * HEXP * DDIM, HEXP, Dd, nullptr, eb1, 2 * HEXP, nullptr,
      ntl, t_e, t_row, idx, gate, HEXP, DDIM);
  k_moe_gemm<EPI_SWIG, true><<<dim3(MAXTILES, 4), 512, 0, stream>>>(
      xb, we1, (size_t)2 * HEXP * DDIM, 0, Cc, nullptr, eb1, 2 * HEXP, Dd,
      ntl, t_e, t_row, idx, gate, HEXP, DDIM);
  k_moe_gemm<EPI_SCAT, false><<<dim3(MAXTILES, 8), 512, 0, stream>>>(
      Cc, we2, (size_t)DDIM * HEXP, 0, nullptr, out, eb2, DDIM, nullptr,
      ntl, t_e, t_row, idx, gate, DDIM, HEXP);

  // ---- SSM branch ----
  k_gemm8<128, EPI_BF16><<<dim3(8, 32), 512, 0, stream>>>(
      xb, wsin, th, nullptr, sbin, nullptr, 0, nullptr, 0, SDIM, DDIM);
  k_im2col<<<16384, 256, 0, stream>>>(th, Dd);
  k_gemm8<128, EPI_BF16><<<dim3(8, 32), 512, 0, stream>>>(
      Dd, wconv, tsq, nullptr, sbc, nullptr, 0, nullptr, 0, SDIM, SDIM * 4);
  k_gemm8<128, EPI_OUT_A><<<dim3(8, 32), 512, 0, stream>>>(
      tsq, wsout, nullptr, out, sbo, bw3 + 1, 3, nullptr, 0, DDIM, SDIM);
}

// Round 8
// 678.581 us; speedup vs baseline: 2.6730x; 1.2860x over previous
//
#include <hip/hip_runtime.h>
#include <hip/hip_bf16.h>
#include <cstdint>

typedef __bf16 bf16_t;
typedef __bf16 bf16x8 __attribute__((ext_vector_type(8)));
typedef float f32x4 __attribute__((ext_vector_type(4)));

#define DEV_INLINE __device__ __forceinline__

#define NTOK 8192
#define DDIM 1024
#define HDIM 4096
#define SDIM 1024
#define NEXP 8
#define HEXP 512
#define TSEQ 2048
#define MAXTILES 136
#define MAXROWS (MAXTILES * 128)

#define VMCNT(n) asm volatile("s_waitcnt vmcnt(" #n ")" ::: "memory")
#define BARF() asm volatile("s_barrier" ::: "memory")

// ---------------- conversion: f32 -> bf16, 8 elems/thread ----------------
__global__ __launch_bounds__(256) void k_f32_to_bf16(const float* __restrict__ src,
                                                     bf16_t* __restrict__ dst, int n8) {
  int i = blockIdx.x * 256 + threadIdx.x;
  if (i >= n8) return;
  const float4* s = (const float4*)src + (size_t)i * 2;
  float4 v0 = s[0], v1 = s[1];
  bf16x8 o;
  o[0] = (bf16_t)v0.x; o[1] = (bf16_t)v0.y; o[2] = (bf16_t)v0.z; o[3] = (bf16_t)v0.w;
  o[4] = (bf16_t)v1.x; o[5] = (bf16_t)v1.y; o[6] = (bf16_t)v1.z; o[7] = (bf16_t)v1.w;
  *((bf16x8*)dst + i) = o;
}

// ------------- conv weight: [S][S][K] f32 -> [S][K*S] bf16 (k-major) -------------
__global__ __launch_bounds__(256) void k_convw(const float* __restrict__ src,
                                               bf16_t* __restrict__ dst) {
  int i = blockIdx.x * 256 + threadIdx.x;
  size_t flat = (size_t)i * 8;
  int s = (int)(flat >> 12);
  int col = (int)(flat & 4095);
  int k = col >> 10;
  int si0 = col & 1023;
  const float* sp = src + (size_t)s * 4096 + k;
  bf16x8 o;
#pragma unroll
  for (int j = 0; j < 8; ++j) o[j] = (bf16_t)sp[(size_t)(si0 + j) * 4];
  *(bf16x8*)(dst + flat) = o;
}

// ------------- im2col: h[8192][1024] -> A2[8192][4096] -------------
__global__ __launch_bounds__(256) void k_im2col(const bf16_t* __restrict__ h,
                                                bf16_t* __restrict__ a2) {
  int i = blockIdx.x * 256 + threadIdx.x;
  size_t flat = (size_t)i * 8;
  int t = (int)(flat >> 12);
  int col = (int)(flat & 4095);
  int k = col >> 10;
  int si = col & 1023;
  int tt = t & (TSEQ - 1);
  bf16x8 v;
#pragma unroll
  for (int j = 0; j < 8; ++j) v[j] = (bf16_t)0.f;
  if (tt - 3 + k >= 0) v = *(const bf16x8*)(h + (size_t)(t - 3 + k) * SDIM + si);
  *(bf16x8*)(a2 + flat) = v;
}

// ------------- MoE bookkeeping -------------
__global__ __launch_bounds__(256) void k_zero(int* cnt, int* fill, int* idx,
                                              float* gate) {
  int i = blockIdx.x * 256 + threadIdx.x;
  if (i < NEXP) { cnt[i] = 0; fill[i] = 0; }
  if (i < MAXROWS) { idx[i] = 0; gate[i] = 0.f; }
}

// histogram with zero global-atomic contention: register-private counts ->
// wave shfl reduce -> 8 LDS atomics/wave -> single write
__global__ __launch_bounds__(1024) void k_count(const int* __restrict__ top2e,
                                                int* __restrict__ cnt) {
  __shared__ int hist[NEXP];
  const int tid = threadIdx.x;
  if (tid < NEXP) hist[tid] = 0;
  __syncthreads();
  int c[NEXP];
#pragma unroll
  for (int e = 0; e < NEXP; ++e) c[e] = 0;
#pragma unroll
  for (int j = 0; j < 2 * NTOK / 1024; ++j) {
    int v = top2e[j * 1024 + tid];
#pragma unroll
    for (int e = 0; e < NEXP; ++e) c[e] += (v == e) ? 1 : 0;
  }
#pragma unroll
  for (int e = 0; e < NEXP; ++e)
    for (int off = 32; off; off >>= 1) c[e] += __shfl_xor(c[e], off);
  if ((tid & 63) == 0) {
#pragma unroll
    for (int e = 0; e < NEXP; ++e) atomicAdd(&hist[e], c[e]);
  }
  __syncthreads();
  if (tid < NEXP) cnt[tid] = hist[tid];
}

__global__ void k_scan(const int* __restrict__ cnt, int* __restrict__ base,
                       int* __restrict__ ntiles, int* __restrict__ tile_e,
                       int* __restrict__ tile_row) {
  if (threadIdx.x == 0 && blockIdx.x == 0) {
    int b = 0, tt = 0;
    for (int e = 0; e < NEXP; ++e) {
      base[e] = b;
      int nt = (cnt[e] + 127) >> 7;
      for (int j = 0; j < nt; ++j) { tile_e[tt] = e; tile_row[tt] = b + j * 128; ++tt; }
      b += nt * 128;
    }
    *ntiles = tt;
  }
}

// two-level scatter: LDS local slots, 8 global atomics per BLOCK (range
// reservation), then direct writes. Slot order within an expert region is
// arbitrary -- fc2's per-token scatter-add is order-invariant.
__global__ __launch_bounds__(256) void k_scatter(const int* __restrict__ top2e,
                                                 const float* __restrict__ top2w,
                                                 const int* __restrict__ base,
                                                 int* __restrict__ fill,
                                                 int* __restrict__ idx,
                                                 float* __restrict__ gate) {
  __shared__ int lcnt[NEXP];
  __shared__ int lbase[NEXP];
  const int tid = threadIdx.x;
  const int t = blockIdx.x * 256 + tid;
  if (tid < NEXP) lcnt[tid] = 0;
  __syncthreads();
  const int e0 = top2e[t * 2 + 0], e1 = top2e[t * 2 + 1];
  const int s0 = atomicAdd(&lcnt[e0], 1);
  const int s1 = atomicAdd(&lcnt[e1], 1);
  __syncthreads();
  if (tid < NEXP) lbase[tid] = atomicAdd(&fill[tid], lcnt[tid]);
  __syncthreads();
  const int p0 = base[e0] + lbase[e0] + s0;
  const int p1 = base[e1] + lbase[e1] + s1;
  idx[p0] = t; gate[p0] = top2w[t * 2 + 0];
  idx[p1] = t; gate[p1] = top2w[t * 2 + 1];
}

// ------------- router: branch softmax [8192,3] + MoE top-2 (no atomics) -------------
__global__ __launch_bounds__(256) void k_router(const float* __restrict__ x,
                                                const float* __restrict__ rW,
                                                const float* __restrict__ rb,
                                                const float* __restrict__ mW,
                                                const float* __restrict__ mb,
                                                float* __restrict__ bw3,
                                                int* __restrict__ top2e,
                                                float* __restrict__ top2w) {
  int wave = threadIdx.x >> 6, lane = threadIdx.x & 63;
  int t = blockIdx.x * 4 + wave;
  const float* xr = x + (size_t)t * DDIM;
  float xv[16];
#pragma unroll
  for (int i = 0; i < 16; i += 4) *(float4*)&xv[i] = *(const float4*)&xr[lane * 16 + i];
  float acc[11];
#pragma unroll
  for (int j = 0; j < 11; ++j) {
    const float* w = (j < 3) ? (rW + j * DDIM) : (mW + (j - 3) * DDIM);
    float s = 0.f;
#pragma unroll
    for (int i = 0; i < 16; i += 4) {
      float4 wv = *(const float4*)&w[lane * 16 + i];
      s += xv[i] * wv.x + xv[i + 1] * wv.y + xv[i + 2] * wv.z + xv[i + 3] * wv.w;
    }
    acc[j] = s;
  }
#pragma unroll
  for (int j = 0; j < 11; ++j)
    for (int off = 32; off; off >>= 1) acc[j] += __shfl_xor(acc[j], off);
  if (lane == 0) {
    float l0 = acc[0] + rb[0], l1 = acc[1] + rb[1], l2 = acc[2] + rb[2];
    float mx = fmaxf(l0, fmaxf(l1, l2));
    float e0 = expf(l0 - mx), e1 = expf(l1 - mx), e2 = expf(l2 - mx);
    float inv = 1.f / (e0 + e1 + e2);
    float w2 = e2 * inv;
    bw3[t * 3 + 0] = e0 * inv; bw3[t * 3 + 1] = e1 * inv; bw3[t * 3 + 2] = w2;
    float lg[8];
#pragma unroll
    for (int e = 0; e < 8; ++e) lg[e] = acc[3 + e] + mb[e];
    int i0 = 0;
#pragma unroll
    for (int e = 1; e < 8; ++e) if (lg[e] > lg[i0]) i0 = e;
    int i1 = -1;
#pragma unroll
    for (int e = 0; e < 8; ++e) {
      if (e == i0) continue;
      if (i1 < 0 || lg[e] > lg[i1]) i1 = e;
    }
    float ee = expf(lg[i1] - lg[i0]);
    float w0 = 1.f / (1.f + ee), w1 = ee / (1.f + ee);
    top2e[t * 2 + 0] = i0; top2e[t * 2 + 1] = i1;
    top2w[t * 2 + 0] = w2 * w0; top2w[t * 2 + 1] = w2 * w1;
  }
}

// =======================================================================
// Dense GEMM (round-5 proven): C[M=8192,N] = A[M,K] @ B[N,K]^T, bf16.
// BM=256, BK=32, 512 thr = 8 waves (2Mx4N). Quad-buffered, tile t+3 staged
// during t, uniform counted vmcnt (never 0 in loop), conflict-free swizzle
// slot' = hi ^ ((row>>1)&3) via pre-swizzled global source + XOR on read.
// =======================================================================
DEV_INLINE void gload16(const bf16_t* g, bf16_t* l) {
  __builtin_amdgcn_global_load_lds((const __attribute__((address_space(1))) void*)g,
                                   (__attribute__((address_space(3))) void*)l, 16, 0, 0);
}

constexpr int EPI_BF16 = 0;   // Cb = bf16(v + bias[col])
constexpr int EPI_OUT_W = 1;  // Cf = scale[row]*(v+bias)
constexpr int EPI_OUT_A = 2;  // Cf += scale[row]*(v+bias)
constexpr int EPI_SWIG = 4;   // Cb = bf16(silu(v+bias)*aux[row,col])
constexpr int EPI_SCAT = 5;   // atomicAdd(Cf[token], gate*(v+bias)) [MoE fc2]

template <int BN_, int EPI>
__global__ __launch_bounds__(512, 2) void k_gemm8(
    const bf16_t* __restrict__ A, const bf16_t* __restrict__ B,
    bf16_t* __restrict__ Cb, float* __restrict__ Cf,
    const float* __restrict__ bias, const float* __restrict__ scale, int sstride,
    const bf16_t* __restrict__ aux, int ldaux,
    int N, int K) {
  constexpr int NF = BN_ / 64;
  constexpr int BUF = 16384 + BN_ * 64;
  __shared__ __align__(16) char lds[4 * BUF];

  const int tid = threadIdx.x;
  const int lane = tid & 63;
  const int wave = tid >> 6;
  const int lr = lane & 15;
  const int hi = lane >> 4;

  const int nbx = gridDim.x, nby = gridDim.y;
  int id = blockIdx.x + nbx * blockIdx.y;
  const int nwg = nbx * nby;
  if ((nwg & 7) == 0) id = (id & 7) * (nwg >> 3) + (id >> 3);
  const int bx = id % nbx;
  const int by = id / nbx;

  const int bm = by * 256;
  const int bn = bx * BN_;
  const int wm = (wave >> 2) * 128;
  const int wn = (wave & 3) * (BN_ / 4);

  const bf16_t* Bb = B + (size_t)bn * K;

  const int srow = tid >> 2;
  const int scol = 8 * ((tid & 3) ^ ((tid >> 3) & 3));
  const bf16_t* Asrc = A + (size_t)(bm + srow) * K + scol;
  const bf16_t* Bsrc = Bb + (size_t)srow * K + scol;
  const size_t r128K = (size_t)128 * K;
  const int NT = K >> 5;

  f32x4 acc[8][NF];
#pragma unroll
  for (int a = 0; a < 8; ++a)
#pragma unroll
    for (int b = 0; b < NF; ++b)
#pragma unroll
      for (int j = 0; j < 4; ++j) acc[a][b][j] = 0.f;

  auto stageA = [&](int t) {
    const bf16_t* g = Asrc + (size_t)t * 32;
    char* l = lds + (t & 3) * BUF + tid * 16;
    gload16(g, (bf16_t*)l);
    gload16(g + r128K, (bf16_t*)(l + 8192));
  };
  auto stageB = [&](int t) {
    const bf16_t* g = Bsrc + (size_t)t * 32;
    char* l = lds + (t & 3) * BUF + 16384 + tid * 16;
    gload16(g, (bf16_t*)l);
    if constexpr (BN_ == 256) gload16(g + r128K, (bf16_t*)(l + 8192));
  };
  auto rdA = [&](int buf, int row) -> bf16x8 {
    int off = buf + (row << 6) + ((hi ^ ((row >> 1) & 3)) << 4);
    return *(const bf16x8*)(lds + off);
  };
  auto rdB = [&](int buf, int row) -> bf16x8 {
    int off = buf + 16384 + (row << 6) + ((hi ^ ((row >> 1) & 3)) << 4);
    return *(const bf16x8*)(lds + off);
  };

  auto tilebody = [&](int t, bool dostage) {
    const int buf = (t & 3) * BUF;
    bf16x8 bfr[NF], afr[4];
#pragma unroll
    for (int ni = 0; ni < NF; ++ni) bfr[ni] = rdB(buf, wn + ni * 16 + lr);
#pragma unroll
    for (int i = 0; i < 4; ++i) afr[i] = rdA(buf, wm + i * 16 + lr);
    if (dostage) stageA(t + 3);
    __builtin_amdgcn_s_setprio(1);
#pragma unroll
    for (int i = 0; i < 4; ++i)
#pragma unroll
      for (int ni = 0; ni < NF; ++ni)
        acc[i][ni] = __builtin_amdgcn_mfma_f32_16x16x32_bf16(afr[i], bfr[ni], acc[i][ni], 0, 0, 0);
    __builtin_amdgcn_s_setprio(0);
#pragma unroll
    for (int i = 0; i < 4; ++i) afr[i] = rdA(buf, wm + 64 + i * 16 + lr);
    if (dostage) stageB(t + 3);
    __builtin_amdgcn_s_setprio(1);
#pragma unroll
    for (int i = 0; i < 4; ++i)
#pragma unroll
      for (int ni = 0; ni < NF; ++ni)
        acc[4 + i][ni] = __builtin_amdgcn_mfma_f32_16x16x32_bf16(afr[i], bfr[ni], acc[4 + i][ni], 0, 0, 0);
    __builtin_amdgcn_s_setprio(0);
  };

  stageA(0); stageB(0); stageA(1); stageB(1); stageA(2); stageB(2);

  for (int t = 0; t < NT - 3; ++t) {
    if constexpr (BN_ == 256) { VMCNT(8); } else { VMCNT(6); }
    BARF();
    tilebody(t, true);
  }
  if constexpr (BN_ == 256) { VMCNT(8); } else { VMCNT(6); }
  BARF();
  tilebody(NT - 3, false);
  if constexpr (BN_ == 256) { VMCNT(4); } else { VMCNT(3); }
  BARF();
  tilebody(NT - 2, false);
  VMCNT(0);
  BARF();
  tilebody(NT - 1, false);

  float bv[NF];
#pragma unroll
  for (int ni = 0; ni < NF; ++ni) bv[ni] = bias[bn + wn + ni * 16 + lr];
#pragma unroll
  for (int mi = 0; mi < 8; ++mi) {
#pragma unroll
    for (int j = 0; j < 4; ++j) {
      const int rowg = bm + wm + mi * 16 + hi * 4 + j;
      float sc = 0.f;
      if constexpr (EPI == EPI_OUT_W || EPI == EPI_OUT_A)
        sc = scale[(size_t)rowg * sstride];
#pragma unroll
      for (int ni = 0; ni < NF; ++ni) {
        const int colg = bn + wn + ni * 16 + lr;
        float v = acc[mi][ni][j] + bv[ni];
        if constexpr (EPI == EPI_BF16) {
          Cb[(size_t)rowg * N + colg] = (bf16_t)v;
        } else if constexpr (EPI == EPI_OUT_W) {
          Cf[(size_t)rowg * N + colg] = sc * v;
        } else if constexpr (EPI == EPI_OUT_A) {
          Cf[(size_t)rowg * N + colg] += sc * v;
        } else {
          float bb = (float)aux[(size_t)rowg * ldaux + colg];
          float s = v / (1.f + __expf(-v));
          Cb[(size_t)rowg * N + colg] = (bf16_t)(s * bb);
        }
      }
    }
  }
}

// =======================================================================
// Sparse MoE GEMM: tile-descriptor driven, BM=BN=128, 8 waves (2Mx4N),
// quad-buffered BK=32 (2 loads/tile -> gate vmcnt(4), peel 4/2/0).
// GA: A rows gathered via idx[] (fc1, A=xb); else slot-linear (fc2, A=Cc).
// EPI_SCAT scatters to out[token] via atomicAdd with per-row gate.
// =======================================================================
template <int EPI, bool GA>
__global__ __launch_bounds__(512, 2) void k_moe_gemm(
    const bf16_t* __restrict__ A, const bf16_t* __restrict__ Bw, size_t zB, int boff,
    bf16_t* __restrict__ Cb, float* __restrict__ Cf,
    const float* __restrict__ bias, int bstride,
    const bf16_t* __restrict__ aux,
    const int* __restrict__ ntiles_p, const int* __restrict__ tile_e,
    const int* __restrict__ tile_row, const int* __restrict__ idx,
    const float* __restrict__ gate,
    int N, int K) {
  constexpr int BUF = 16384;  // 128*64 (A) + 128*64 (B) bytes
  __shared__ __align__(16) char lds[4 * BUF];

  const int tid = threadIdx.x;
  const int lane = tid & 63;
  const int wave = tid >> 6;
  const int lr = lane & 15;
  const int hi = lane >> 4;

  const int nbx = gridDim.x, nby = gridDim.y;
  int id = blockIdx.x + nbx * blockIdx.y;
  const int nwg = nbx * nby;
  if ((nwg & 7) == 0) id = (id & 7) * (nwg >> 3) + (id >> 3);
  const int bx = id % nbx;
  const int by = id / nbx;

  const int ntiles = *ntiles_p;
  if (bx >= ntiles) return;
  const int e = tile_e[bx];
  const int bm = tile_row[bx];
  const int bn = by * 128;
  const int wm = (wave >> 2) * 64;
  const int wn = (wave & 3) * 32;

  const int srow = tid >> 2;
  const int scol = 8 * ((tid & 3) ^ ((tid >> 3) & 3));
  const int arow = bm + srow;
  const int atok = GA ? idx[arow] : arow;
  const bf16_t* Asrc = A + (size_t)atok * K + scol;
  const bf16_t* Bsrc = Bw + (size_t)e * zB + (size_t)(boff + bn + srow) * K + scol;
  const int NT = K >> 5;

  f32x4 acc[4][2];
#pragma unroll
  for (int a = 0; a < 4; ++a)
#pragma unroll
    for (int b = 0; b < 2; ++b)
#pragma unroll
      for (int j = 0; j < 4; ++j) acc[a][b][j] = 0.f;

  auto stage = [&](int t) {
    char* l = lds + (t & 3) * BUF + tid * 16;
    gload16(Asrc + (size_t)t * 32, (bf16_t*)l);
    gload16(Bsrc + (size_t)t * 32, (bf16_t*)(l + 8192));
  };
  auto rdA = [&](int buf, int row) -> bf16x8 {
    int off = buf + (row << 6) + ((hi ^ ((row >> 1) & 3)) << 4);
    return *(const bf16x8*)(lds + off);
  };
  auto rdB = [&](int buf, int row) -> bf16x8 {
    int off = buf + 8192 + (row << 6) + ((hi ^ ((row >> 1) & 3)) << 4);
    return *(const bf16x8*)(lds + off);
  };

  auto tilebody = [&](int t, bool dostage) {
    const int buf = (t & 3) * BUF;
    bf16x8 bfr[2], afr[4];
#pragma unroll
    for (int ni = 0; ni < 2; ++ni) bfr[ni] = rdB(buf, wn + ni * 16 + lr);
#pragma unroll
    for (int i = 0; i < 4; ++i) afr[i] = rdA(buf, wm + i * 16 + lr);
    if (dostage) stage(t + 3);
    __builtin_amdgcn_s_setprio(1);
#pragma unroll
    for (int i = 0; i < 4; ++i)
#pragma unroll
      for (int ni = 0; ni < 2; ++ni)
        acc[i][ni] = __builtin_amdgcn_mfma_f32_16x16x32_bf16(afr[i], bfr[ni], acc[i][ni], 0, 0, 0);
    __builtin_amdgcn_s_setprio(0);
  };

  stage(0); stage(1); stage(2);

  for (int t = 0; t < NT - 3; ++t) {
    VMCNT(4);
    BARF();
    tilebody(t, true);
  }
  VMCNT(4); BARF(); tilebody(NT - 3, false);
  VMCNT(2); BARF(); tilebody(NT - 2, false);
  VMCNT(0); BARF(); tilebody(NT - 1, false);

  const float* bp = bias + (size_t)e * bstride + boff;
  float bv[2];
#pragma unroll
  for (int ni = 0; ni < 2; ++ni) bv[ni] = bp[bn + wn + ni * 16 + lr];
#pragma unroll
  for (int mi = 0; mi < 4; ++mi) {
#pragma unroll
    for (int j = 0; j < 4; ++j) {
      const int slot = bm + wm + mi * 16 + hi * 4 + j;
      float sc = 0.f;
      int tok = 0;
      if constexpr (EPI == EPI_SCAT) { sc = gate[slot]; tok = idx[slot]; }
#pragma unroll
      for (int ni = 0; ni < 2; ++ni) {
        const int colg = bn + wn + ni * 16 + lr;
        float v = acc[mi][ni][j] + bv[ni];
        if constexpr (EPI == EPI_BF16) {
          Cb[(size_t)slot * N + colg] = (bf16_t)v;
        } else if constexpr (EPI == EPI_SWIG) {
          float bb = (float)aux[(size_t)slot * N + colg];
          float s = v / (1.f + __expf(-v));
          Cb[(size_t)slot * N + colg] = (bf16_t)(s * bb);
        } else {
          if (sc != 0.f) atomicAdd(&Cf[(size_t)tok * N + colg], sc * v);
        }
      }
    }
  }
}

// ---------------------------------------------------------------------------
extern "C" void kernel_launch(void* const* d_in, const int* in_sizes, int n_in,
                              void* d_out, int out_size, void* d_ws, size_t ws_size,
                              hipStream_t stream) {
  (void)in_sizes; (void)n_in; (void)out_size; (void)ws_size;
  const float* x    = (const float*)d_in[0];
  const float* rW   = (const float*)d_in[1];
  const float* rb   = (const float*)d_in[2];
  const float* d1W  = (const float*)d_in[3];
  const float* d1b  = (const float*)d_in[4];
  const float* d2W  = (const float*)d_in[5];
  const float* d2b  = (const float*)d_in[6];
  const float* sWin = (const float*)d_in[7];
  const float* sbin = (const float*)d_in[8];
  const float* sWc  = (const float*)d_in[9];
  const float* sbc  = (const float*)d_in[10];
  const float* sWo  = (const float*)d_in[11];
  const float* sbo  = (const float*)d_in[12];
  const float* mW   = (const float*)d_in[13];
  const float* mb   = (const float*)d_in[14];
  const float* eW1  = (const float*)d_in[15];
  const float* eb1  = (const float*)d_in[16];
  const float* eW2  = (const float*)d_in[17];
  const float* eb2  = (const float*)d_in[18];
  float* out = (float*)d_out;

  char* ws = (char*)d_ws;
  size_t off = 0;
  auto alloc = [&](size_t bytes) -> void* {
    void* p = ws + off;
    off += (bytes + 255) & ~(size_t)255;
    return p;
  };
  bf16_t* xb    = (bf16_t*)alloc((size_t)NTOK * DDIM * 2);
  bf16_t* wd1   = (bf16_t*)alloc((size_t)2 * HDIM * DDIM * 2);
  bf16_t* wd2   = (bf16_t*)alloc((size_t)DDIM * HDIM * 2);
  bf16_t* wsin  = (bf16_t*)alloc((size_t)SDIM * DDIM * 2);
  bf16_t* wconv = (bf16_t*)alloc((size_t)SDIM * SDIM * 4 * 2);
  bf16_t* wsout = (bf16_t*)alloc((size_t)DDIM * SDIM * 2);
  bf16_t* we1   = (bf16_t*)alloc((size_t)NEXP * 2 * HEXP * DDIM * 2);
  bf16_t* we2   = (bf16_t*)alloc((size_t)NEXP * DDIM * HEXP * 2);
  bf16_t* Cc    = (bf16_t*)alloc((size_t)NTOK * HDIM * 2);  // fc1-a/swiglu | MoE swiglu (slot)
  bf16_t* Dd    = (bf16_t*)alloc((size_t)NTOK * HDIM * 2);  // fc1-b | MoE fc1-b (slot) | im2col
  bf16_t* th    = (bf16_t*)alloc((size_t)NTOK * SDIM * 2);
  bf16_t* tsq   = (bf16_t*)alloc((size_t)NTOK * SDIM * 2);
  float*  bw3   = (float*)alloc((size_t)NTOK * 3 * 4);
  int*    top2e = (int*)alloc((size_t)NTOK * 2 * 4);
  float*  top2w = (float*)alloc((size_t)NTOK * 2 * 4);
  int*    cnt   = (int*)alloc(NEXP * 4);
  int*    fill  = (int*)alloc(NEXP * 4);
  int*    basep = (int*)alloc((NEXP + 1) * 4);
  int*    ntl   = (int*)alloc(4);
  int*    t_e   = (int*)alloc(MAXTILES * 4);
  int*    t_row = (int*)alloc(MAXTILES * 4);
  int*    idx   = (int*)alloc(MAXROWS * 4);
  float*  gate  = (float*)alloc(MAXROWS * 4);

  // conversions + router + MoE bookkeeping
  k_f32_to_bf16<<<4096, 256, 0, stream>>>(x, xb, NTOK * DDIM / 8);
  k_f32_to_bf16<<<4096, 256, 0, stream>>>(d1W, wd1, 2 * HDIM * DDIM / 8);
  k_f32_to_bf16<<<2048, 256, 0, stream>>>(d2W, wd2, DDIM * HDIM / 8);
  k_f32_to_bf16<<<512, 256, 0, stream>>>(sWin, wsin, SDIM * DDIM / 8);
  k_convw<<<2048, 256, 0, stream>>>(sWc, wconv);
  k_f32_to_bf16<<<512, 256, 0, stream>>>(sWo, wsout, DDIM * SDIM / 8);
  k_f32_to_bf16<<<4096, 256, 0, stream>>>(eW1, we1, NEXP * 2 * HEXP * DDIM / 8);
  k_f32_to_bf16<<<2048, 256, 0, stream>>>(eW2, we2, NEXP * DDIM * HEXP / 8);
  k_zero<<<(MAXROWS + 255) / 256, 256, 0, stream>>>(cnt, fill, idx, gate);
  k_router<<<2048, 256, 0, stream>>>(x, rW, rb, mW, mb, bw3, top2e, top2w);
  k_count<<<1, 1024, 0, stream>>>(top2e, cnt);
  k_scan<<<1, 64, 0, stream>>>(cnt, basep, ntl, t_e, t_row);
  k_scatter<<<NTOK / 256, 256, 0, stream>>>(top2e, top2w, basep, fill, idx, gate);

  // ---- dense branch: fc1-b, fc1-a(+fused swiglu), d2 -> out ----
  k_gemm8<256, EPI_BF16><<<dim3(16, 32), 512, 0, stream>>>(
      xb, wd1 + (size_t)HDIM * DDIM, Dd, nullptr, d1b + HDIM, nullptr, 0, nullptr, 0,
      HDIM, DDIM);
  k_gemm8<256, EPI_SWIG><<<dim3(16, 32), 512, 0, stream>>>(
      xb, wd1, Cc, nullptr, d1b, nullptr, 0, Dd, HDIM, HDIM, DDIM);
  k_gemm8<128, EPI_OUT_W><<<dim3(8, 32), 512, 0, stream>>>(
      Cc, wd2, nullptr, out, d2b, bw3, 3, nullptr, 0, DDIM, HDIM);

  // ---- sparse MoE: gathered fc1-b, fc1-a(+swiglu), fc2 scatter ----
  k_moe_gemm<EPI_BF16, true><<<dim3(MAXTILES, 4), 512, 0, stream>>>(
      xb, we1, (size_t)2 * HEXP * DDIM, HEXP, Dd, nullptr, eb1, 2 * HEXP, nullptr,
      ntl, t_e, t_row, idx, gate, HEXP, DDIM);
  k_moe_gemm<EPI_SWIG, true><<<dim3(MAXTILES, 4), 512, 0, stream>>>(
      xb, we1, (size_t)2 * HEXP * DDIM, 0, Cc, nullptr, eb1, 2 * HEXP, Dd,
      ntl, t_e, t_row, idx, gate, HEXP, DDIM);
  k_moe_gemm<EPI_SCAT, false><<<dim3(MAXTILES, 8), 512, 0, stream>>>(
      Cc, we2, (size_t)DDIM * HEXP, 0, nullptr, out, eb2, DDIM, nullptr,
      ntl, t_e, t_row, idx, gate, DDIM, HEXP);

  // ---- SSM branch ----
  k_gemm8<128, EPI_BF16><<<dim3(8, 32), 512, 0, stream>>>(
      xb, wsin, th, nullptr, sbin, nullptr, 0, nullptr, 0, SDIM, DDIM);
  k_im2col<<<16384, 256, 0, stream>>>(th, Dd);
  k_gemm8<128, EPI_BF16><<<dim3(8, 32), 512, 0, stream>>>(
      Dd, wconv, tsq, nullptr, sbc, nullptr, 0, nullptr, 0, SDIM, SDIM * 4);
  k_gemm8<128, EPI_OUT_A><<<dim3(8, 32), 512, 0, stream>>>(
      tsq, wsout, nullptr, out, sbo, bw3 + 1, 3, nullptr, 0, DDIM, SDIM);
}